// Round 1
// baseline (946.564 us; speedup 1.0000x reference)
//
#include <hip/hip_runtime.h>
#include <math.h>

// ModulationIndex on MI355X.
// pha: (4,16,10,4,2048) f32 in [-pi,pi];  amp: (4,16,30,4,2048) f32 >= 0
// out: (4,16,10,30) f32
//
// One workgroup per (b,c,s) group: 4*16*4 = 256 workgroups == 256 CUs.
// Phase 1: bins (u8 packed 4-per-u32) in LDS, cutoffs bit-match np.linspace(f32).
// Phase 2: stage amp tiles (transposed, stride 33 to avoid bank conflicts),
//          lanes = 32 a-columns x 2 t; ds_add_f32 scatter into sums[p][k][32].
//          Column 30 is a constant-1.0 "ones" column => counts come for free.
// Epilogue: entropy per (p,a) -> ws[(bcpa)*4 + s]; kernel2 means over s.

#define FP_ 10
#define FA_ 30
#define K_  18
#define T_  2048
#define TC_ 128   // t-tile staged in LDS

__global__ __launch_bounds__(512, 1)
void mi_main(const float* __restrict__ pha, const float* __restrict__ amp,
             float* __restrict__ ws) {
  __shared__ float    c_lds[19];
  __shared__ unsigned binsw[FP_ * 512];      // 4 bins packed per u32
  __shared__ float    amp_lds[TC_ * 33];     // [t][a], padded to 33
  __shared__ float    sums[FP_ * K_ * 32];   // [p][k][a32]; a=30 -> counts

  const int tid = threadIdx.x;
  const int g   = blockIdx.x;       // (b*16+c)*4 + s
  const int s   = g & 3;
  const int bc  = g >> 2;           // b*16 + c
  const long pha_base = (long)bc * (FP_ * 4L * T_) + (long)s * T_;   // bc*81920 + s*2048
  const long amp_base = (long)bc * (FA_ * 4L * T_) + (long)s * T_;   // bc*245760 + s*2048

  // --- init: cutoff table (bit-exact np.linspace(-pi, pi, 19) computed in f64,
  // cast to f32), zero accumulators, constant columns of the amp tile.
  if (tid < 19) {
    const double PI_D = 3.14159265358979323846264338327950288;
    const double step = (2.0 * PI_D) / 18.0;
    c_lds[tid] = (tid == 18) ? (float)PI_D
                             : (float)(-PI_D + (double)tid * step);
  }
  for (int i = tid; i < FP_ * K_ * 32; i += 512) sums[i] = 0.0f;
  if (tid < TC_) { amp_lds[tid * 33 + 30] = 1.0f; amp_lds[tid * 33 + 31] = 0.0f; }
  __syncthreads();

  // --- phase 1: bins. Each thread owns 4 consecutive t for each p.
  const float PI_F    = 3.14159274101257324f;   // (float)pi
  const float INVSTEP = 2.8647890f;             // ~18/(2pi); guess only, corrected below
  #pragma unroll
  for (int p = 0; p < FP_; ++p) {
    const float4 v = *(const float4*)(pha + pha_base + (long)p * (4L * T_) + tid * 4);
    float xs[4] = {v.x, v.y, v.z, v.w};
    unsigned pk = 0;
    #pragma unroll
    for (int j = 0; j < 4; ++j) {
      const float x = xs[j];
      int gi = (int)((x + PI_F) * INVSTEP);
      gi = min(17, max(0, gi));
      // searchsorted-left semantics: bin b satisfies c_b < x <= c_{b+1}
      if (x <= c_lds[gi]) gi -= 1;
      else if (x > c_lds[gi + 1]) gi += 1;
      gi = min(17, max(0, gi));
      pk |= ((unsigned)gi) << (8 * j);
    }
    binsw[p * 512 + tid] = pk;
  }
  __syncthreads();

  const int lane = tid & 63;
  const int wv   = tid >> 6;    // 8 waves
  const int a32  = lane & 31;   // a column (30=ones, 31=zero pad)
  const int th   = lane >> 5;   // which t of the pair
  const int tl0  = wv * 16;     // 16 t per wave per tile

  for (int tile = 0; tile < T_ / TC_; ++tile) {
    const int t0 = tile * TC_;
    // stage amp tile: 30 rows x 128 t, transposed into amp_lds[t][a]
    for (int idx = tid; idx < 30 * (TC_ / 4); idx += 512) {   // 960
      const int a  = idx >> 5;        // 0..29
      const int tq = idx & 31;        // float4 index within tile
      const float4 v = *(const float4*)(amp + amp_base + (long)a * (4L * T_) + t0 + tq * 4);
      float* dst = &amp_lds[(tq * 4) * 33 + a];
      dst[0]  = v.x;
      dst[33] = v.y;
      dst[66] = v.z;
      dst[99] = v.w;
    }
    __syncthreads();

    // consume: per wave 8 t-pair iterations
    unsigned bw[FP_];
    #pragma unroll
    for (int i = 0; i < 8; ++i) {
      if ((i & 1) == 0) {
        const int w = (t0 + tl0 + 2 * i) >> 2;   // bins word covers t..t+3
        #pragma unroll
        for (int p = 0; p < FP_; ++p) bw[p] = binsw[p * 512 + w];
      }
      const int   tl   = tl0 + 2 * i + th;
      const float ampv = amp_lds[tl * 33 + a32];
      const int   pos  = 8 * (2 * (i & 1) + th);
      #pragma unroll
      for (int p = 0; p < FP_; ++p) {
        const int k = (bw[p] >> pos) & 0xFF;
        atomicAdd(&sums[p * (K_ * 32) + k * 32 + a32], ampv);
      }
    }
    __syncthreads();
  }

  // --- epilogue: one thread per (p, a)
  if (tid < FP_ * FA_) {
    const int p = tid / FA_;
    const int a = tid - p * FA_;
    float m[K_];
    float tot = 0.0f;
    #pragma unroll
    for (int k = 0; k < K_; ++k) {
      const float cnt = sums[p * (K_ * 32) + k * 32 + 30];
      const float sv  = sums[p * (K_ * 32) + k * 32 + a];
      const float mk  = sv / (cnt + 1e-9f);
      m[k] = mk;
      tot += mk;
    }
    const float denom = tot + 1e-9f;
    float ent = 0.0f;
    #pragma unroll
    for (int k = 0; k < K_; ++k) {
      const float pr = m[k] / denom;
      ent += pr * logf(pr + 1e-9f);
    }
    const float L  = logf(18.0f);
    const float mi = (L + ent) / L;
    ws[(((long)bc * FP_ + p) * FA_ + a) * 4 + s] = mi;
  }
}

__global__ __launch_bounds__(256)
void mi_reduce(const float* __restrict__ ws, float* __restrict__ out) {
  const int i = blockIdx.x * 256 + threadIdx.x;
  if (i < 4 * 16 * FP_ * FA_) {
    const float* w = ws + (long)i * 4;
    out[i] = (((w[0] + w[1]) + w[2]) + w[3]) * 0.25f;
  }
}

extern "C" void kernel_launch(void* const* d_in, const int* in_sizes, int n_in,
                              void* d_out, int out_size, void* d_ws, size_t ws_size,
                              hipStream_t stream) {
  const float* pha = (const float*)d_in[0];
  const float* amp = (const float*)d_in[1];
  float* out = (float*)d_out;
  float* ws  = (float*)d_ws;   // needs 19200*4 floats = 307200 B

  hipLaunchKernelGGL(mi_main, dim3(256), dim3(512), 0, stream, pha, amp, ws);
  hipLaunchKernelGGL(mi_reduce, dim3((19200 + 255) / 256), dim3(256), 0, stream, ws, out);
}

// Round 2
// 123.991 us; speedup vs baseline: 7.6341x; 7.6341x over previous
//
#include <hip/hip_runtime.h>
#include <math.h>

// ModulationIndex as MFMA GEMM:
// amp_sums[p*18+k, a] = sum_t onehot[pk, t] * amp[a, t]  -- 192x32x2048 f16 GEMM
// per (b,c,s) group; 256 groups = 256 workgroups (1/CU), 512 threads.
// A (onehot) generated in registers from packed bins; B (amp) split hi/lo f16
// (lo scaled x4096 to avoid denorm flush), staged per 512-t tile in LDS with
// register prefetch. 8 waves = 2 m-halves x 4 k-quarters; tree-reduce partials.

#define FP_ 10
#define FA_ 30
#define K_  18
#define T_  2048
#define TC_ 512
#define NTILE 4
#define RS_ 260   // amp row stride in u32 (256 data + 4 pad, 16B-aligned)
#define NT_ 512

typedef _Float16 half8 __attribute__((ext_vector_type(8)));
typedef float    f32x4 __attribute__((ext_vector_type(4)));

// LDS layout (dynamic):
//   [0,128)                      c_lds (19 f32 cutoffs)
//   [128, 128+20480)             binsw: 10 x 512 u32 (4 bins/u32)
//   [+0, +33280)                 amp_h: 32 rows x 260 u32 (f16 pairs)
//   [+0, +33280)                 amp_l
//   [+0, +50688)                 red: 4 slots x 96 x 33 f32 (tree + final C)
#define LDS_BYTES (128 + 20480 + 33280 + 33280 + 50688)

__global__ __launch_bounds__(NT_, 2)
void mi_main(const float* __restrict__ pha, const float* __restrict__ amp,
             float* __restrict__ ws) {
  extern __shared__ unsigned char smem[];
  float*    c_lds = (float*)smem;
  unsigned* binsw = (unsigned*)(smem + 128);
  unsigned* amp_h = (unsigned*)(smem + 128 + 20480);
  unsigned* amp_l = (unsigned*)(smem + 128 + 20480 + 33280);
  float*    red   = (float*)(smem + 128 + 20480 + 66560);

  const int tid  = threadIdx.x;
  const int lane = tid & 63;
  const int wv   = tid >> 6;
  const int quad = lane >> 4;
  const int lc   = lane & 15;
  const int q    = wv >> 1;   // k-quarter 0..3
  const int gh   = wv & 1;    // m-half 0..1

  const int g  = blockIdx.x;
  const int s  = g & 3;
  const int bc = g >> 2;
  const long pha_base = (long)bc * (FP_ * 4L * T_) + (long)s * T_;
  const long amp_base = (long)bc * (FA_ * 4L * T_) + (long)s * T_;

  // cutoffs: bit-exact np.linspace(-pi, pi, 19) (f64 math, f32 cast)
  if (tid < 19) {
    const double PI_D = 3.14159265358979323846264338327950288;
    const double step = (2.0 * PI_D) / 18.0;
    c_lds[tid] = (tid == 18) ? (float)PI_D : (float)(-PI_D + (double)tid * step);
  }
  // static B rows: 30 = ones (counts), 31 = zero pad
  for (int i = tid; i < RS_; i += NT_) {
    amp_h[30 * RS_ + i] = 0x3C003C00u;
    amp_h[31 * RS_ + i] = 0u;
    amp_l[30 * RS_ + i] = 0u;
    amp_l[31 * RS_ + i] = 0u;
  }
  __syncthreads();

  // --- bins: thread owns t = 4*tid..4*tid+3 for each p; pack 4 u8/u32.
  const float PI_F    = 3.14159274101257324f;
  const float INVSTEP = 2.8647890f;
  #pragma unroll
  for (int p = 0; p < FP_; ++p) {
    const float4 v = *(const float4*)(pha + pha_base + (long)p * (4L * T_) + tid * 4);
    float xs[4] = {v.x, v.y, v.z, v.w};
    unsigned pk = 0;
    #pragma unroll
    for (int j = 0; j < 4; ++j) {
      const float x = xs[j];
      int gi = (int)((x + PI_F) * INVSTEP);
      gi = min(17, max(0, gi));
      if (x <= c_lds[gi]) gi -= 1;
      else if (x > c_lds[gi + 1]) gi += 1;
      gi = min(17, max(0, gi));
      pk |= ((unsigned)gi) << (8 * j);
    }
    binsw[p * 512 + tid] = pk;
  }

  // --- amp staging setup; prefetch tile 0 into registers.
  const bool stager = tid < 480;
  const int a_row = tid >> 4;           // 0..29
  const int seg   = tid & 15;           // 32-t segment within tile
  const float* gsrc = amp + amp_base + (long)a_row * (4L * T_) + seg * 32;
  float4 vreg[8];
  if (stager) {
    #pragma unroll
    for (int j = 0; j < 8; ++j) vreg[j] = *(const float4*)(gsrc + j * 4);
  }

  f32x4 acch[6][2], accl[6][2];
  #pragma unroll
  for (int mt = 0; mt < 6; ++mt) {
    acch[mt][0] = (f32x4){0.f,0.f,0.f,0.f}; acch[mt][1] = (f32x4){0.f,0.f,0.f,0.f};
    accl[mt][0] = (f32x4){0.f,0.f,0.f,0.f}; accl[mt][1] = (f32x4){0.f,0.f,0.f,0.f};
  }

  for (int tile = 0; tile < NTILE; ++tile) {
    // write staged registers -> LDS (f16 hi + f16 lo*4096)
    if (stager) {
      unsigned hw[16], lw[16];
      #pragma unroll
      for (int j = 0; j < 8; ++j) {
        const float xv[4] = {vreg[j].x, vreg[j].y, vreg[j].z, vreg[j].w};
        #pragma unroll
        for (int e = 0; e < 4; e += 2) {
          _Float16 h0 = (_Float16)xv[e];
          _Float16 h1 = (_Float16)xv[e + 1];
          _Float16 l0 = (_Float16)((xv[e]     - (float)h0) * 4096.0f);
          _Float16 l1 = (_Float16)((xv[e + 1] - (float)h1) * 4096.0f);
          const unsigned uh0 = (unsigned)__builtin_bit_cast(unsigned short, h0);
          const unsigned uh1 = (unsigned)__builtin_bit_cast(unsigned short, h1);
          const unsigned ul0 = (unsigned)__builtin_bit_cast(unsigned short, l0);
          const unsigned ul1 = (unsigned)__builtin_bit_cast(unsigned short, l1);
          hw[j * 2 + e / 2] = uh0 | (uh1 << 16);
          lw[j * 2 + e / 2] = ul0 | (ul1 << 16);
        }
      }
      unsigned* dh = &amp_h[a_row * RS_ + seg * 16];
      unsigned* dl = &amp_l[a_row * RS_ + seg * 16];
      #pragma unroll
      for (int k4 = 0; k4 < 4; ++k4) {
        ((uint4*)dh)[k4] = make_uint4(hw[4*k4], hw[4*k4+1], hw[4*k4+2], hw[4*k4+3]);
        ((uint4*)dl)[k4] = make_uint4(lw[4*k4], lw[4*k4+1], lw[4*k4+2], lw[4*k4+3]);
      }
    }
    __syncthreads();
    // prefetch next tile while computing this one
    if (stager && tile < NTILE - 1) {
      #pragma unroll
      for (int j = 0; j < 8; ++j)
        vreg[j] = *(const float4*)(gsrc + (tile + 1) * TC_ + j * 4);
    }

    #pragma unroll
    for (int ci = 0; ci < 4; ++ci) {
      const int cl   = q * 4 + ci;          // local kchunk (32 t) in tile
      const int boff = cl * 16 + quad * 4;  // u32 offset within amp row
      const half8 bh0 = __builtin_bit_cast(half8, *(const uint4*)&amp_h[lc * RS_ + boff]);
      const half8 bh1 = __builtin_bit_cast(half8, *(const uint4*)&amp_h[(16 + lc) * RS_ + boff]);
      const half8 bl0 = __builtin_bit_cast(half8, *(const uint4*)&amp_l[lc * RS_ + boff]);
      const half8 bl1 = __builtin_bit_cast(half8, *(const uint4*)&amp_l[(16 + lc) * RS_ + boff]);
      const int wbase = tile * 128 + cl * 8 + quad * 2;   // binsw word index
      #pragma unroll
      for (int mt = 0; mt < 6; ++mt) {
        const int row = gh * 96 + mt * 16 + lc;   // 0..191
        int p = row / 18;  p = min(p, 9);
        const unsigned kb = (unsigned)(row - p * 18);   // >=18 for pad rows: never matches
        const uint2 w01 = *(const uint2*)&binsw[p * 512 + wbase];
        unsigned aw[4];
        #pragma unroll
        for (int j2 = 0; j2 < 4; ++j2) {
          const unsigned w  = (j2 < 2) ? w01.x : w01.y;
          const unsigned sh = (unsigned)(j2 & 1) * 16u;
          const unsigned b0 = (w >> sh) & 0xFFu;
          const unsigned b1 = (w >> (sh + 8u)) & 0xFFu;
          aw[j2] = (b0 == kb ? 0x3C00u : 0u) | (b1 == kb ? 0x3C000000u : 0u);
        }
        const half8 af = __builtin_bit_cast(half8, make_uint4(aw[0], aw[1], aw[2], aw[3]));
        acch[mt][0] = __builtin_amdgcn_mfma_f32_16x16x32_f16(af, bh0, acch[mt][0], 0, 0, 0);
        accl[mt][0] = __builtin_amdgcn_mfma_f32_16x16x32_f16(af, bl0, accl[mt][0], 0, 0, 0);
        acch[mt][1] = __builtin_amdgcn_mfma_f32_16x16x32_f16(af, bh1, acch[mt][1], 0, 0, 0);
        accl[mt][1] = __builtin_amdgcn_mfma_f32_16x16x32_f16(af, bl1, accl[mt][1], 0, 0, 0);
      }
    }
    __syncthreads();
  }

  // combine hi + lo/4096 -> 48 f32 per lane
  f32x4 acc[6][2];
  #pragma unroll
  for (int mt = 0; mt < 6; ++mt) {
    acc[mt][0] = acch[mt][0] + accl[mt][0] * 2.44140625e-4f;
    acc[mt][1] = acch[mt][1] + accl[mt][1] * 2.44140625e-4f;
  }

  // --- tree reduction of 4 k-quarter partials per m-half (no atomics).
  // C/D layout (16x16x32): col = lane&15, row = quad*4 + reg.
  float* slotA = &red[(gh * 2 + (q & 1)) * 96 * 33];   // generic slot ptr helpers below
  (void)slotA;
  {
    #define STORE48(S) do { \
      _Pragma("unroll") for (int mt = 0; mt < 6; ++mt) \
      _Pragma("unroll") for (int n = 0; n < 2; ++n) \
      _Pragma("unroll") for (int r = 0; r < 4; ++r) \
        (S)[(mt * 16 + quad * 4 + r) * 33 + n * 16 + lc] = acc[mt][n][r]; } while (0)
    #define ADD48(S) do { \
      _Pragma("unroll") for (int mt = 0; mt < 6; ++mt) \
      _Pragma("unroll") for (int n = 0; n < 2; ++n) \
      _Pragma("unroll") for (int r = 0; r < 4; ++r) \
        acc[mt][n][r] += (S)[(mt * 16 + quad * 4 + r) * 33 + n * 16 + lc]; } while (0)

    if (q >= 2) { float* S = &red[(gh * 2 + (q - 2)) * 96 * 33]; STORE48(S); }
    __syncthreads();
    if (q < 2)  { float* S = &red[(gh * 2 + q) * 96 * 33];       ADD48(S); }
    __syncthreads();
    if (q == 1) { float* S = &red[(gh * 2) * 96 * 33];           STORE48(S); }
    __syncthreads();
    if (q == 0) { float* S = &red[(gh * 2) * 96 * 33];           ADD48(S); }
    __syncthreads();
    // final C into red[row*33 + col], rows 0..191
    if (q == 0) {
      #pragma unroll
      for (int mt = 0; mt < 6; ++mt)
        #pragma unroll
        for (int n = 0; n < 2; ++n)
          #pragma unroll
          for (int r = 0; r < 4; ++r)
            red[(gh * 96 + mt * 16 + quad * 4 + r) * 33 + n * 16 + lc] = acc[mt][n][r];
    }
    __syncthreads();
  }

  // --- epilogue: one thread per (p, a)
  if (tid < FP_ * FA_) {
    const int p = tid / FA_;
    const int a = tid - p * FA_;
    float m[K_];
    float tot = 0.0f;
    #pragma unroll
    for (int k = 0; k < K_; ++k) {
      const float cnt = red[(p * K_ + k) * 33 + 30];
      const float sv  = red[(p * K_ + k) * 33 + a];
      const float mk  = sv / (cnt + 1e-9f);
      m[k] = mk;
      tot += mk;
    }
    const float denom = tot + 1e-9f;
    float ent = 0.0f;
    #pragma unroll
    for (int k = 0; k < K_; ++k) {
      const float pr = m[k] / denom;
      ent += pr * logf(pr + 1e-9f);
    }
    const float L  = logf(18.0f);
    const float mi = (L + ent) / L;
    ws[(((long)bc * FP_ + p) * FA_ + a) * 4 + s] = mi;
  }
}

__global__ __launch_bounds__(256)
void mi_reduce(const float* __restrict__ ws, float* __restrict__ out) {
  const int i = blockIdx.x * 256 + threadIdx.x;
  if (i < 4 * 16 * FP_ * FA_) {
    const float* w = ws + (long)i * 4;
    out[i] = (((w[0] + w[1]) + w[2]) + w[3]) * 0.25f;
  }
}

extern "C" void kernel_launch(void* const* d_in, const int* in_sizes, int n_in,
                              void* d_out, int out_size, void* d_ws, size_t ws_size,
                              hipStream_t stream) {
  const float* pha = (const float*)d_in[0];
  const float* amp = (const float*)d_in[1];
  float* out = (float*)d_out;
  float* ws  = (float*)d_ws;   // 19200*4 floats = 307200 B

  static bool attr_set = false;
  if (!attr_set) {
    hipFuncSetAttribute((const void*)mi_main,
                        hipFuncAttributeMaxDynamicSharedMemorySize, LDS_BYTES);
    attr_set = true;
  }
  hipLaunchKernelGGL(mi_main, dim3(256), dim3(NT_), LDS_BYTES, stream, pha, amp, ws);
  hipLaunchKernelGGL(mi_reduce, dim3((19200 + 255) / 256), dim3(256), 0, stream, ws, out);
}